// Round 7
// baseline (254.697 us; speedup 1.0000x reference)
//
#include <hip/hip_runtime.h>
#include <math.h>

#define Bn 32
#define Nn 2000
#define En 32000
#define Vn 100000
#define Dn 128
#define Rn 39
#define Kn 8

#define SUBS 8
#define NPS (Nn / SUBS)   // 250 nodes per sub-block
#define CH 32             // gather chunks per graph
#define EQ (En / 4)       // 8000 edge-quads per graph

// Workspace layout (ws_size far exceeds; no aliasing):
//   [ 0)          : cnt     int  [B*N*R]      =  9,984,000
//   [ 9,984,000)  : a       float[B*N*K]     =  2,048,000
//   [12,032,000)  : partial float[B*CH*9*128]=  4,718,592
//
// blockIdx.x = graph everywhere -> all blocks of graph b share (b mod 8) XCD
// -> graph-local edge/cnt data stays in that XCD's L2 (R2 evidence: 9x fetch cut).

// K1: 8 blocks/graph, each owns dst-range [s0,s0+250). int4 scan (4 edges/iter).
__global__ __launch_bounds__(1024) void cnt_kernel(const int* __restrict__ edge_index,
                                                   const int* __restrict__ edge_type,
                                                   int* __restrict__ cnt) {
    int b = blockIdx.x, sub = blockIdx.y;
    int s0 = sub * NPS;
    __shared__ int loc[NPS * Rn];                 // 9750 ints = 39 KB
    for (int i = threadIdx.x; i < NPS * Rn; i += 1024) loc[i] = 0;
    __syncthreads();
    const int4* dst4 = (const int4*)(edge_index + (b * 2 + 1) * En);
    const int4* et4  = (const int4*)(edge_type + b * En);
    for (int q = threadIdx.x; q < EQ; q += 1024) {
        int4 d = dst4[q];
        int4 t = et4[q];
        int x;
        x = d.x - s0; if ((unsigned)x < NPS) atomicAdd(&loc[x * Rn + t.x], 1);
        x = d.y - s0; if ((unsigned)x < NPS) atomicAdd(&loc[x * Rn + t.y], 1);
        x = d.z - s0; if ((unsigned)x < NPS) atomicAdd(&loc[x * Rn + t.z], 1);
        x = d.w - s0; if ((unsigned)x < NPS) atomicAdd(&loc[x * Rn + t.w], 1);
    }
    __syncthreads();
    int* g = cnt + ((size_t)b * Nn + s0) * Rn;
    for (int i = threadIdx.x; i < NPS * Rn; i += 1024) g[i] = loc[i];
}

// K2: 8 blocks/graph own src-ranges. Each edge passes the src-filter in exactly
// one block, so the dependent cnt lookup happens E times total (inv_kernel
// fused away). ONE LDS atomic/edge into s[src][t] (stride 39, coprime to 32
// banks), then a[n][k] = s @ comp.
__global__ __launch_bounds__(1024) void a_kernel(const int* __restrict__ edge_index,
                                                 const int* __restrict__ edge_type,
                                                 const int* __restrict__ cnt,
                                                 const float* __restrict__ comp,
                                                 float* __restrict__ a) {
    int b = blockIdx.x, sub = blockIdx.y;
    int s0 = sub * NPS;
    __shared__ float s[NPS * Rn];                 // 39 KB
    __shared__ float comp_l[Rn * Kn];
    for (int i = threadIdx.x; i < NPS * Rn; i += 1024) s[i] = 0.0f;
    if (threadIdx.x < Rn * Kn) comp_l[threadIdx.x] = comp[threadIdx.x];
    __syncthreads();
    const int4* src4 = (const int4*)(edge_index + (b * 2 + 0) * En);
    const int4* dst4 = (const int4*)(edge_index + (b * 2 + 1) * En);
    const int4* et4  = (const int4*)(edge_type + b * En);
    const int*  cb   = cnt + (size_t)b * Nn * Rn;
    for (int q = threadIdx.x; q < EQ; q += 1024) {
        int4 sv = src4[q];
        int4 dv = dst4[q];
        int4 tv = et4[q];
        int x;
        x = sv.x - s0; if ((unsigned)x < NPS)
            atomicAdd(&s[x * Rn + tv.x], 1.0f / (float)cb[dv.x * Rn + tv.x]);
        x = sv.y - s0; if ((unsigned)x < NPS)
            atomicAdd(&s[x * Rn + tv.y], 1.0f / (float)cb[dv.y * Rn + tv.y]);
        x = sv.z - s0; if ((unsigned)x < NPS)
            atomicAdd(&s[x * Rn + tv.z], 1.0f / (float)cb[dv.z * Rn + tv.z]);
        x = sv.w - s0; if ((unsigned)x < NPS)
            atomicAdd(&s[x * Rn + tv.w], 1.0f / (float)cb[dv.w * Rn + tv.w]);
    }
    __syncthreads();
    float* g = a + ((size_t)b * Nn + s0) * Kn;
    for (int i = threadIdx.x; i < NPS * Kn; i += 1024) {   // 2000 outputs
        int n = i >> 3, k = i & 7;
        float acc = 0.0f;
        const float* srow = &s[n * Rn];
        for (int t = 0; t < Rn; t++) acc += srow[t] * comp_l[t * Kn + k];
        g[i] = acc;
    }
}

// K3: wave-autonomous gather, unroll-4 (4 independent 512B row loads in
// flight). Each wave handles ~16 nodes; 4-wave LDS combine; direct store.
__global__ __launch_bounds__(256) void gather_kernel(const int* __restrict__ node_ids,
                                                     const float* __restrict__ emb,
                                                     const float* __restrict__ a,
                                                     float* __restrict__ partial) {
    int b = blockIdx.x, c = blockIdx.y;
    int lane = threadIdx.x & 63, wv = threadIdx.x >> 6;   // 4 waves
    int W = c * 4 + wv;                                   // wave id in [0,128)
    float acc[18];
#pragma unroll
    for (int k = 0; k < 18; k++) acc[k] = 0.0f;
    const int*   nb = node_ids + b * Nn;
    const float* ab = a + (size_t)b * Nn * Kn;
    for (int n0 = W; n0 < Nn; n0 += 4 * 128) {
        bool  has[4];
        int   nn[4];
        float2 v[4];
        float4 a0[4], a1[4];
#pragma unroll
        for (int i = 0; i < 4; i++) {
            int n = n0 + i * 128;
            has[i] = n < Nn;
            nn[i]  = has[i] ? n : n0;
        }
#pragma unroll
        for (int i = 0; i < 4; i++) {
            int nid = nb[nn[i]];
            v[i] = has[i] ? ((const float2*)(emb + (size_t)nid * Dn))[lane]
                          : make_float2(0.f, 0.f);
            const float4* ar = (const float4*)(ab + (size_t)nn[i] * Kn);
            a0[i] = ar[0]; a1[i] = ar[1];
        }
#pragma unroll
        for (int i = 0; i < 4; i++) {
            float w[9] = {a0[i].x, a0[i].y, a0[i].z, a0[i].w,
                          a1[i].x, a1[i].y, a1[i].z, a1[i].w, 1.0f};
#pragma unroll
            for (int k = 0; k < 9; k++) {
                acc[2 * k]     += w[k] * v[i].x;
                acc[2 * k + 1] += w[k] * v[i].y;
            }
        }
    }
    __shared__ float red[4 * 9 * Dn];             // 18 KB
#pragma unroll
    for (int k = 0; k < 9; k++) {
        ((float2*)&red[(wv * 9 + k) * Dn])[lane] = make_float2(acc[2 * k], acc[2 * k + 1]);
    }
    __syncthreads();
    float* g = partial + ((size_t)b * CH + c) * 9 * Dn;
    for (int i = threadIdx.x; i < 9 * Dn; i += 256)
        g[i] = red[i] + red[9 * Dn + i] + red[18 * Dn + i] + red[27 * Dn + i];
}

// K4: fused reduce + 9 matvecs + L2-norm. One block per graph; matrices are
// L2-resident per XCD (4 graphs/XCD share them).
__global__ __launch_bounds__(256) void final_kernel(const float* __restrict__ partial,
                                                    const float* __restrict__ root,
                                                    const float* __restrict__ bases,
                                                    const float* __restrict__ bias,
                                                    float* __restrict__ out) {
    int b = blockIdx.x;
    __shared__ float ts[9 * Dn];
    for (int i = threadIdx.x; i < 9 * Dn; i += 256) {
        float s = 0.0f;
        const float* p = partial + (size_t)b * CH * 9 * Dn + i;
        for (int c = 0; c < CH; c++) s += p[c * 9 * Dn];
        ts[i] = s;
    }
    __syncthreads();
    int d = threadIdx.x & (Dn - 1), h = threadIdx.x >> 7;
    float gp = 0.0f;
#pragma unroll
    for (int m = 0; m < 9; m++) {
        const float* M  = (m == 8) ? root : bases + (size_t)m * Dn * Dn;
        const float* tm = &ts[m * Dn];
        for (int j = h * 64; j < h * 64 + 64; j++) gp += tm[j] * M[j * Dn + d];
    }
    __shared__ float gsh[2][Dn];
    gsh[h][d] = gp;
    __syncthreads();
    float g = 0.0f;
    if (h == 0) g = (float)Nn * bias[d] + gsh[0][d] + gsh[1][d];
    float ss = g * g;                              // h==1 lanes contribute 0
#pragma unroll
    for (int off = 32; off > 0; off >>= 1) ss += __shfl_down(ss, off, 64);
    __shared__ float s4[4];
    if ((threadIdx.x & 63) == 0) s4[threadIdx.x >> 6] = ss;
    __syncthreads();
    float nrm = sqrtf(s4[0] + s4[1] + s4[2] + s4[3]);
    if (h == 0) out[b * Dn + d] = g / fmaxf(nrm, 1e-5f);
}

extern "C" void kernel_launch(void* const* d_in, const int* in_sizes, int n_in,
                              void* d_out, int out_size, void* d_ws, size_t ws_size,
                              hipStream_t stream) {
    const int*   node_ids   = (const int*)d_in[0];
    const int*   edge_index = (const int*)d_in[1];
    const int*   edge_type  = (const int*)d_in[2];
    const float* embedding  = (const float*)d_in[3];
    const float* bases      = (const float*)d_in[4];
    const float* comp       = (const float*)d_in[5];
    const float* root       = (const float*)d_in[6];
    const float* bias       = (const float*)d_in[7];
    float*       out        = (float*)d_out;

    char* w = (char*)d_ws;
    int*   cnt     = (int*)  (w + 0);
    float* a       = (float*)(w + 9984000);
    float* partial = (float*)(w + 12032000);

    cnt_kernel   <<<dim3(Bn, SUBS), 1024, 0, stream>>>(edge_index, edge_type, cnt);
    a_kernel     <<<dim3(Bn, SUBS), 1024, 0, stream>>>(edge_index, edge_type, cnt, comp, a);
    gather_kernel<<<dim3(Bn, CH),   256,  0, stream>>>(node_ids, embedding, a, partial);
    final_kernel <<<Bn, 256, 0, stream>>>(partial, root, bases, bias, out);
}

// Round 8
// 156.218 us; speedup vs baseline: 1.6304x; 1.6304x over previous
//
#include <hip/hip_runtime.h>
#include <math.h>

#define Bn 32
#define Nn 2000
#define En 32000
#define Vn 100000
#define Dn 128
#define Rn 39
#define Kn 8

#define SUBS 8
#define NPS (Nn / SUBS)   // 250 dst nodes per sub-block
#define WPG 128           // gather waves (= partial chunks) per graph
#define EQ (En / 4)       // 8000 edge-quads per graph

// Workspace layout (no aliasing):
//   [ 0)          : inv     float[B*E]          =  4,096,000
//   [ 4,096,000)  : a       float[B*N*K]        =  2,048,000
//   [ 6,144,000)  : partial float[B*WPG*9*128]  = 18,874,368
//   [25,018,368)  : gmat    float[B*9*128]      =    147,456
//
// blockIdx.x = graph everywhere -> all blocks of graph b share (b mod 8) XCD
// -> graph-local edge data stays in that XCD's L2 (R2 evidence: 9x fetch cut).
// R6 lesson: never shrink active-CU count for a latency-bound phase.

// K1: fused cnt+inv. 8 blocks/graph own dst-ranges. Pass 1: LDS histogram of
// (dst,rel) over the block's range. Pass 2: re-scan (L2-hot) edges, write
// inv[e]=1/cnt for owned edges (each edge owned by exactly one block).
// cnt never touches global memory; no random L2 lookups anywhere.
__global__ __launch_bounds__(1024) void cntinv_kernel(const int* __restrict__ edge_index,
                                                      const int* __restrict__ edge_type,
                                                      float* __restrict__ inv) {
    int b = blockIdx.x, sub = blockIdx.y;
    int s0 = sub * NPS;
    __shared__ int loc[NPS * Rn];                 // 9750 ints = 39 KB
    for (int i = threadIdx.x; i < NPS * Rn; i += 1024) loc[i] = 0;
    __syncthreads();
    const int4* dst4 = (const int4*)(edge_index + (b * 2 + 1) * En);
    const int4* et4  = (const int4*)(edge_type + b * En);
    for (int q = threadIdx.x; q < EQ; q += 1024) {
        int4 d = dst4[q];
        int4 t = et4[q];
        int x;
        x = d.x - s0; if ((unsigned)x < NPS) atomicAdd(&loc[x * Rn + t.x], 1);
        x = d.y - s0; if ((unsigned)x < NPS) atomicAdd(&loc[x * Rn + t.y], 1);
        x = d.z - s0; if ((unsigned)x < NPS) atomicAdd(&loc[x * Rn + t.z], 1);
        x = d.w - s0; if ((unsigned)x < NPS) atomicAdd(&loc[x * Rn + t.w], 1);
    }
    __syncthreads();
    float* ivb = inv + (size_t)b * En;
    for (int q = threadIdx.x; q < EQ; q += 1024) {
        int4 d = dst4[q];
        int4 t = et4[q];
        int e = 4 * q, x;
        x = d.x - s0; if ((unsigned)x < NPS) ivb[e]     = 1.0f / (float)loc[x * Rn + t.x];
        x = d.y - s0; if ((unsigned)x < NPS) ivb[e + 1] = 1.0f / (float)loc[x * Rn + t.y];
        x = d.z - s0; if ((unsigned)x < NPS) ivb[e + 2] = 1.0f / (float)loc[x * Rn + t.z];
        x = d.w - s0; if ((unsigned)x < NPS) ivb[e + 3] = 1.0f / (float)loc[x * Rn + t.w];
    }
}

// K2: 8 blocks/graph own src-ranges. Pure streaming scan (src,et,inv all
// sequential), ONE LDS atomic/edge into s[src][t] (stride 39, coprime to 32
// banks -> conflict-free), then a[n][k] = s @ comp.
__global__ __launch_bounds__(1024) void a_kernel(const int* __restrict__ edge_index,
                                                 const int* __restrict__ edge_type,
                                                 const float* __restrict__ inv,
                                                 const float* __restrict__ comp,
                                                 float* __restrict__ a) {
    int b = blockIdx.x, sub = blockIdx.y;
    int s0 = sub * NPS;
    __shared__ float s[NPS * Rn];                 // 39 KB
    __shared__ float comp_l[Rn * Kn];
    for (int i = threadIdx.x; i < NPS * Rn; i += 1024) s[i] = 0.0f;
    if (threadIdx.x < Rn * Kn) comp_l[threadIdx.x] = comp[threadIdx.x];
    __syncthreads();
    const int4*   src4 = (const int4*)(edge_index + (b * 2 + 0) * En);
    const int4*   et4  = (const int4*)(edge_type + b * En);
    const float4* iv4  = (const float4*)(inv + (size_t)b * En);
    for (int q = threadIdx.x; q < EQ; q += 1024) {
        int4 sv = src4[q];
        int4 tv = et4[q];
        float4 iv = iv4[q];
        int x;
        x = sv.x - s0; if ((unsigned)x < NPS) atomicAdd(&s[x * Rn + tv.x], iv.x);
        x = sv.y - s0; if ((unsigned)x < NPS) atomicAdd(&s[x * Rn + tv.y], iv.y);
        x = sv.z - s0; if ((unsigned)x < NPS) atomicAdd(&s[x * Rn + tv.z], iv.z);
        x = sv.w - s0; if ((unsigned)x < NPS) atomicAdd(&s[x * Rn + tv.w], iv.w);
    }
    __syncthreads();
    float* g = a + ((size_t)b * Nn + s0) * Kn;
    for (int i = threadIdx.x; i < NPS * Kn; i += 1024) {   // 2000 outputs
        int n = i >> 3, k = i & 7;
        float acc = 0.0f;
        const float* srow = &s[n * Rn];
        for (int t = 0; t < Rn; t++) acc += srow[t] * comp_l[t * Kn + k];
        g[i] = acc;
    }
}

// K3: wave-autonomous gather. Each of 128 waves/graph owns node set
// {n : n mod 128 == W} (~16 nodes), unroll-4 row loads for MLP, and writes its
// own partial chunk [W][9][128] with coalesced float2 stores. No LDS, no syncs.
__global__ __launch_bounds__(256) void gather_kernel(const int* __restrict__ node_ids,
                                                     const float* __restrict__ emb,
                                                     const float* __restrict__ a,
                                                     float* __restrict__ partial) {
    int b = blockIdx.x;
    int lane = threadIdx.x & 63, wv = threadIdx.x >> 6;
    int W = blockIdx.y * 4 + wv;                  // wave id in [0, WPG)
    float acc[18];
#pragma unroll
    for (int k = 0; k < 18; k++) acc[k] = 0.0f;
    const int*   nb = node_ids + b * Nn;
    const float* ab = a + (size_t)b * Nn * Kn;
    for (int n0 = W; n0 < Nn; n0 += 4 * WPG) {
        bool   has[4];
        int    nn[4];
        float2 v[4];
        float4 a0[4], a1[4];
#pragma unroll
        for (int i = 0; i < 4; i++) {
            int n = n0 + i * WPG;
            has[i] = n < Nn;
            nn[i]  = has[i] ? n : n0;
        }
#pragma unroll
        for (int i = 0; i < 4; i++) {
            int nid = nb[nn[i]];
            v[i] = has[i] ? ((const float2*)(emb + (size_t)nid * Dn))[lane]
                          : make_float2(0.f, 0.f);
            const float4* ar = (const float4*)(ab + (size_t)nn[i] * Kn);
            a0[i] = ar[0]; a1[i] = ar[1];
        }
#pragma unroll
        for (int i = 0; i < 4; i++) {
            float w[9] = {a0[i].x, a0[i].y, a0[i].z, a0[i].w,
                          a1[i].x, a1[i].y, a1[i].z, a1[i].w, 1.0f};
#pragma unroll
            for (int k = 0; k < 9; k++) {
                acc[2 * k]     += w[k] * v[i].x;
                acc[2 * k + 1] += w[k] * v[i].y;
            }
        }
    }
    float2* gp = (float2*)(partial + ((size_t)b * WPG + W) * 9 * Dn);
#pragma unroll
    for (int k = 0; k < 9; k++)
        gp[k * 64 + lane] = make_float2(acc[2 * k], acc[2 * k + 1]);
}

// K4: one block per (graph, matrix m): reduce 128 chunks (d-coalesced,
// unroll-4 ILP), then m<8 -> bases[m] @ t_m ; m==8 -> root @ s.
__global__ __launch_bounds__(256) void matvec_kernel(const float* __restrict__ partial,
                                                     const float* __restrict__ root,
                                                     const float* __restrict__ bases,
                                                     float* __restrict__ gmat) {
    int b = blockIdx.x, m = blockIdx.y;
    int d = threadIdx.x & (Dn - 1), h = threadIdx.x >> 7;
    __shared__ float ts[Dn];
    __shared__ float tsh[2][Dn];
    const float* p = partial + (size_t)b * WPG * 9 * Dn + m * Dn + d;
    float s0 = 0.f, s1 = 0.f, s2 = 0.f, s3 = 0.f;
    for (int c = h; c < WPG; c += 8) {            // 16 iters x 4 accumulators
        s0 += p[(size_t)(c    ) * 9 * Dn];
        s1 += p[(size_t)(c + 2) * 9 * Dn];
        s2 += p[(size_t)(c + 4) * 9 * Dn];
        s3 += p[(size_t)(c + 6) * 9 * Dn];
    }
    tsh[h][d] = (s0 + s1) + (s2 + s3);
    __syncthreads();
    if (h == 0) ts[d] = tsh[0][d] + tsh[1][d];
    __syncthreads();
    const float* M = (m == 8) ? root : bases + (size_t)m * Dn * Dn;
    float g = 0.0f;
    for (int j = h * 64; j < h * 64 + 64; j++) g += ts[j] * M[j * Dn + d];
    __syncthreads();
    tsh[h][d] = g;
    __syncthreads();
    if (h == 0) gmat[((size_t)b * 9 + m) * Dn + d] = tsh[0][d] + tsh[1][d];
}

// K5: sum the 9 matvec outputs, add bias term, L2-normalize.
__global__ __launch_bounds__(128) void norm_kernel(const float* __restrict__ gmat,
                                                   const float* __restrict__ bias,
                                                   float* __restrict__ out) {
    int b = blockIdx.x, d = threadIdx.x;
    float g = (float)Nn * bias[d];
    const float* gb = gmat + (size_t)b * 9 * Dn + d;
#pragma unroll
    for (int m = 0; m < 9; m++) g += gb[m * Dn];
    float ss = g * g;
#pragma unroll
    for (int off = 32; off > 0; off >>= 1) ss += __shfl_down(ss, off, 64);
    __shared__ float s2[2];
    if ((threadIdx.x & 63) == 0) s2[threadIdx.x >> 6] = ss;
    __syncthreads();
    float nrm = sqrtf(s2[0] + s2[1]);
    out[b * Dn + d] = g / fmaxf(nrm, 1e-5f);
}

extern "C" void kernel_launch(void* const* d_in, const int* in_sizes, int n_in,
                              void* d_out, int out_size, void* d_ws, size_t ws_size,
                              hipStream_t stream) {
    const int*   node_ids   = (const int*)d_in[0];
    const int*   edge_index = (const int*)d_in[1];
    const int*   edge_type  = (const int*)d_in[2];
    const float* embedding  = (const float*)d_in[3];
    const float* bases      = (const float*)d_in[4];
    const float* comp       = (const float*)d_in[5];
    const float* root       = (const float*)d_in[6];
    const float* bias       = (const float*)d_in[7];
    float*       out        = (float*)d_out;

    char* w = (char*)d_ws;
    float* inv     = (float*)(w + 0);
    float* a       = (float*)(w + 4096000);
    float* partial = (float*)(w + 6144000);
    float* gmat    = (float*)(w + 25018368);

    cntinv_kernel<<<dim3(Bn, SUBS),    1024, 0, stream>>>(edge_index, edge_type, inv);
    a_kernel     <<<dim3(Bn, SUBS),    1024, 0, stream>>>(edge_index, edge_type, inv, comp, a);
    gather_kernel<<<dim3(Bn, WPG / 4), 256,  0, stream>>>(node_ids, embedding, a, partial);
    matvec_kernel<<<dim3(Bn, 9),       256,  0, stream>>>(partial, root, bases, gmat);
    norm_kernel  <<<Bn, 128, 0, stream>>>(gmat, bias, out);
}